// Round 6
// baseline (226.766 us; speedup 1.0000x reference)
//
#include <hip/hip_runtime.h>
#include <hip/hip_bf16.h>
#include <stdint.h>

// ObjectDetectionLoss (SSD MultiBox) — MI355X / gfx950
// B=64, N=16800, C=21. Output: 3 fp32 scalars.
//
// Round-6. Lessons: r2 = no hot global atomics; r3 = no per-lane clustered
// LDS-atomic histogram (64-way serialization, SQ_LDS_BANK_CONFLICT=175K);
// r4/r5 = container died twice with an 8.7MB workspace (possible ws_size
// overflow -> GPU fault) => stay within r3's PROVEN 4.44MB footprint.
//
//   K1 k_perdata (64x66 blocks, batch-aligned): sl1/ce per anchor -> ce_neg;
//      per-block pos stats -> plain float4 stores. No histogram, no atomics.
//   K2 k_select (64x1024): load batch values once (float4 -> LDS b128) with
//      FUSED 256-bin histogram (top-8 IEEE bits) via wave-ballot aggregation;
//      suffix-scan 256 bins -> boundary bin + rank; 3 refine passes over the
//      23 mantissa bits -> exact k-th value T; sum(v>T)+r*T (tie-exact).
//   K3 k_final (1x64): reduce over batches.

#define NB 64
#define NN 16800
#define NC 21
#define BPB 66                    // blocks per batch (66*256 = 16896 >= 16800)
#define NBLK1 (NB * BPB)          // 4224
#define FP32_EPS_F 1.1920928955078125e-07f

// ---------------- workspace layout (bytes) — total 4,369,664 (< r3's proven 4,436,480)
#define OFF_PARTIAL 0u            // float4 [4224] = 67584
#define OFF_FLB     67584u        // double [64]
#define OFF_FLL     68096u        // double [64]
#define OFF_FPN     68608u        // int    [64] (+pad to 68864)
#define OFF_CENEG   68864u        // float  [NB*NN] = 4300800 -> end 4369664

// ===================== K1: per-anchor =====================
__global__ __launch_bounds__(256) void k_perdata(
    const float* __restrict__ p_bboxs, const float* __restrict__ g_bboxs,
    const float* __restrict__ p_labels, const int* __restrict__ g_labels,
    const float* __restrict__ ancs,
    float* __restrict__ ce_neg, float4* __restrict__ partial)
{
    __shared__ float lab[256 * NC];            // 21504 B
    __shared__ float st[4];                    // pos, sl1, ce

    const int tid = threadIdx.x;
    const int b = blockIdx.x / BPB;
    const int j = blockIdx.x - b * BPB;
    const int nbase = j * 256;
    const int nrem = NN - nbase;
    const int nact = nrem < 256 ? nrem : 256;  // 256, or 160 for j==65
    const bool valid = tid < nact;

    if (tid < 4) st[tid] = 0.f;

    // stage p_labels tile, coalesced float4 (nact*21 divisible by 4)
    {
        const float4* src = (const float4*)(p_labels + ((size_t)b * NN + nbase) * NC);
        float4* dst = (float4*)lab;
        const int nv = nact * NC / 4;          // 1344 or 840
        for (int t = tid; t < nv; t += 256) dst[t] = src[t];
    }
    __syncthreads();

    if (valid) {
        const int idx = b * NN + nbase + tid;
        const float4 p = ((const float4*)p_bboxs)[idx];
        const float4 g = ((const float4*)g_bboxs)[idx];
        const float4 a = ((const float4*)ancs)[nbase + tid];
        const int gl = g_labels[idx];

        // regression targets + SmoothL1 (beta=1), summed over 4 coords
        const float tx = 10.0f * (g.x - a.x) / a.z;
        const float ty = 10.0f * (g.y - a.y) / a.w;
        const float tw = 5.0f * __logf(g.z / a.z);
        const float th = 5.0f * __logf(g.w / a.w);
        float sl1 = 0.f, d, ad;
        d = p.x - tx; ad = fabsf(d); sl1 += (ad < 1.f) ? 0.5f * d * d : ad - 0.5f;
        d = p.y - ty; ad = fabsf(d); sl1 += (ad < 1.f) ? 0.5f * d * d : ad - 0.5f;
        d = p.z - tw; ad = fabsf(d); sl1 += (ad < 1.f) ? 0.5f * d * d : ad - 0.5f;
        d = p.w - th; ad = fabsf(d); sl1 += (ad < 1.f) ? 0.5f * d * d : ad - 0.5f;

        // cross entropy: lse - x[gl]
        const float* row = lab + tid * NC;     // stride 21 (odd): 2-way alias, free
        float m = row[0];
        #pragma unroll
        for (int c = 1; c < NC; ++c) m = fmaxf(m, row[c]);
        float s = 0.f;
        #pragma unroll
        for (int c = 0; c < NC; ++c) s += __expf(row[c] - m);
        const float lse = m + __logf(s);
        const float ce = fmaxf(lse - row[gl], 0.f);  // >=0 -> bits order-monotonic

        const bool pos = gl > 0;
        ce_neg[idx] = pos ? 0.f : ce;          // coalesced

        // per-block positive stats (~5 pos threads): LDS atomics only
        if (pos) {
            atomicAdd(&st[0], 1.f);
            atomicAdd(&st[1], sl1);
            atomicAdd(&st[2], ce);
        }
    }
    __syncthreads();
    if (tid == 0) partial[blockIdx.x] = make_float4(st[0], st[1], st[2], 0.f);
}

// ===================== K2: per-batch exact top-k sum =====================
__global__ __launch_bounds__(1024) void k_select(
    const float* __restrict__ ce_neg, const float4* __restrict__ partial,
    double* __restrict__ flb, double* __restrict__ fll, int* __restrict__ fpn)
{
    __shared__ uint4   vals4[NN / 4];          // 67200 B (16B aligned)
    __shared__ uint32_t hist[256];
    __shared__ uint32_t h2[256];
    __shared__ float s_stats[4];
    __shared__ uint32_t s_cur;
    __shared__ int s_need;
    __shared__ double dpart[16];

    uint32_t* vals = (uint32_t*)vals4;
    const int tid = threadIdx.x, lane = tid & 63, wid = tid >> 6;
    const int b = blockIdx.x;

    if (tid < 4) s_stats[tid] = 0.f;
    if (tid < 256) { hist[tid] = 0u; }
    __syncthreads();

    // ---- load batch values (float4), store LDS (b128), FUSED ballot-histogram ----
    // bin = bits>>23 (sign always 0). One LDS atomic per DISTINCT bin per wave
    // per component (~8 iters per ballot loop) — r3's 64-way serialization gone.
    {
        const float4* src = (const float4*)(ce_neg + (size_t)b * NN);
        for (int i = tid; i < NN / 4; i += 1024) {
            const float4 v = src[i];
            const uint4 u = make_uint4(__float_as_uint(v.x), __float_as_uint(v.y),
                                       __float_as_uint(v.z), __float_as_uint(v.w));
            vals4[i] = u;
            uint32_t comp[4] = {u.x, u.y, u.z, u.w};
            #pragma unroll
            for (int c = 0; c < 4; ++c) {
                const uint32_t dg = comp[c] >> 23;
                unsigned long long act = __ballot(true);   // active lanes of this wave
                while (act) {
                    const int leader = __ffsll((long long)act) - 1;
                    const uint32_t dl = __shfl(dg, leader);
                    const unsigned long long same = __ballot(dg == dl) & act;
                    if (lane == leader) atomicAdd(&hist[dl], (uint32_t)__popcll(same));
                    act &= ~same;
                }
            }
        }
    }

    // ---- reduce per-block stats (66 entries) ----
    if (tid < BPB) {
        const float4 p0 = partial[b * BPB + tid];
        if (p0.x != 0.f) {
            atomicAdd(&s_stats[0], p0.x);
            atomicAdd(&s_stats[1], p0.y);
            atomicAdd(&s_stats[2], p0.z);
        }
    }
    __syncthreads();

    const int pos = (int)(s_stats[0] + 0.5f);
    int k = 3 * pos;                           // NEG_RATIO
    if (k > NN) k = NN;
    if (k < 1) k = 1;                          // pos==0 masked in k_final

    // ---- suffix-scan 256 bins (descending), single wave ----
    if (wid == 0) {
        uint32_t c4[4]; uint32_t cnt = 0;
        #pragma unroll
        for (int t = 0; t < 4; ++t) { c4[t] = hist[255 - (4 * lane + t)]; cnt += c4[t]; }
        uint32_t ic = cnt;
        #pragma unroll
        for (int off = 1; off < 64; off <<= 1) {
            const uint32_t tc = __shfl_up(ic, off);
            if (lane >= off) ic += tc;
        }
        const int exC = (int)(ic - cnt);
        if (exC < k && k <= (int)ic) {         // exactly one lane
            int need = k - exC;
            #pragma unroll
            for (int t = 0; t < 4; ++t) {
                const int c = (int)c4[t];
                if (need <= c) {
                    s_cur = (uint32_t)(255 - (4 * lane + t)) << 23;
                    s_need = need;
                    break;
                }
                need -= c;
            }
        }
    }
    __syncthreads();

    // ---- exact refine of 23 mantissa bits: (sh,nbins)=(15,256),(7,256),(0,128) ----
    // candidates spread ~uniformly over mantissa digits -> plain LDS atomics fine
    #pragma unroll
    for (int p = 0; p < 3; ++p) {
        const int sh = (p == 0) ? 15 : (p == 1) ? 7 : 0;
        const uint32_t nb = (p == 2) ? 128u : 256u;
        const uint32_t bm = nb - 1u;
        const uint32_t msk = (p == 0) ? 0xFF800000u : (p == 1) ? 0xFFFF8000u : 0xFFFFFF80u;
        if (tid < 256) h2[tid] = 0u;
        __syncthreads();
        const uint32_t cur = s_cur;
        for (int i = tid; i < NN; i += 1024) {
            const uint32_t v = vals[i];
            if ((v & msk) == cur) atomicAdd(&h2[(v >> sh) & bm], 1u);
        }
        __syncthreads();
        if (tid == 0) {
            int need = s_need;
            for (int dg = (int)nb - 1; dg >= 0; --dg) {
                const int c = (int)h2[dg];
                if (need <= c) { s_cur = cur | ((uint32_t)dg << sh); s_need = need; break; }
                need -= c;
            }
        }
        __syncthreads();
    }

    // ---- tie-exact top-k sum: sum(v > T) + r*T ----
    const uint32_t T = s_cur;
    const int rf = s_need;
    double loc = 0.0;
    for (int i = tid; i < NN; i += 1024) {
        const uint32_t v = vals[i];
        if (v > T) loc += (double)__uint_as_float(v);
    }
    #pragma unroll
    for (int off = 32; off > 0; off >>= 1) loc += __shfl_down(loc, off);
    if (lane == 0) dpart[wid] = loc;
    __syncthreads();
    if (tid == 0) {
        double tot = 0.0;
        for (int w = 0; w < 16; ++w) tot += dpart[w];
        tot += (double)rf * (double)__uint_as_float(T);
        flb[b] = (double)s_stats[1];
        fll[b] = (double)s_stats[2] + tot;
        fpn[b] = pos;
    }
}

// ===================== K3: final reduction over B =====================
__global__ __launch_bounds__(64) void k_final(
    const double* __restrict__ flb, const double* __restrict__ fll,
    const int* __restrict__ fpn, float* __restrict__ out)
{
    const int t = threadIdx.x;                 // 64 == NB
    const double lb = flb[t];
    const double ll = fll[t];
    const int pn = fpn[t];
    const double nm = (pn > 0) ? 1.0 : 0.0;
    const float pf = fmaxf((float)pn, FP32_EPS_F);
    const double inv = nm / (double)pf;
    double tb = lb * inv;
    double tl = ll * inv;
    double tt = tb + tl;                       // COEFF = (1,1)
    #pragma unroll
    for (int off = 32; off > 0; off >>= 1) {
        tt += __shfl_down(tt, off);
        tb += __shfl_down(tb, off);
        tl += __shfl_down(tl, off);
    }
    if (t == 0) {
        out[0] = (float)(tt / (double)NB);
        out[1] = (float)(tb / (double)NB);
        out[2] = (float)(tl / (double)NB);
    }
}

// ===================== launcher =====================
extern "C" void kernel_launch(void* const* d_in, const int* in_sizes, int n_in,
                              void* d_out, int out_size, void* d_ws, size_t ws_size,
                              hipStream_t stream)
{
    const float* p_bboxs  = (const float*)d_in[0];
    const float* g_bboxs  = (const float*)d_in[1];
    const float* p_labels = (const float*)d_in[2];
    const int*   g_labels = (const int*)d_in[3];
    const float* ancs     = (const float*)d_in[4];
    float* out = (float*)d_out;

    char* ws = (char*)d_ws;
    float4* partial = (float4*)(ws + OFF_PARTIAL);
    double* flb     = (double*)(ws + OFF_FLB);
    double* fll     = (double*)(ws + OFF_FLL);
    int*    fpn     = (int*)   (ws + OFF_FPN);
    float*  ce_neg  = (float*) (ws + OFF_CENEG);

    // no memset: every workspace byte read is written first (no global atomics)

    k_perdata<<<NBLK1, 256, 0, stream>>>(
        p_bboxs, g_bboxs, p_labels, g_labels, ancs, ce_neg, partial);

    k_select<<<NB, 1024, 0, stream>>>(ce_neg, partial, flb, fll, fpn);

    k_final<<<1, 64, 0, stream>>>(flb, fll, fpn, out);
}

// Round 7
// 195.783 us; speedup vs baseline: 1.1583x; 1.1583x over previous
//
#include <hip/hip_runtime.h>
#include <hip/hip_bf16.h>
#include <stdint.h>

// ObjectDetectionLoss (SSD MultiBox) — MI355X / gfx950
// B=64, N=16800, C=21. Output: 3 fp32 scalars.
//
// Round-7. Lessons: r2 = no hot global atomics; r3 = no per-lane clustered
// LDS-atomic histogram; r6 = tid==0 serial bin-walks (256 dependent LDS reads
// x ~130cy x 3 passes ~= 40us) dominated k_select -> replace with the
// wave-parallel suffix-scan pick used by the coarse phase.
//
//   K1 k_perdata (64x66 blocks, batch-aligned): sl1/ce per anchor -> ce_neg;
//      per-block pos stats -> plain float4 stores. Global loads hoisted above
//      the staging barrier to overlap HBM latency.
//   K2 k_select (64x1024): load batch values once (float4 -> LDS b128) with
//      fused 256-bin ballot-histogram; wave-parallel suffix-scan pick at every
//      level (coarse 256 + refine 256/256/128) -> exact k-th value T;
//      sum(v>T)+r*T (tie-exact fp64).
//   K3 k_final (1x64): reduce over batches.

#define NB 64
#define NN 16800
#define NC 21
#define BPB 66                    // blocks per batch (66*256 = 16896 >= 16800)
#define NBLK1 (NB * BPB)          // 4224
#define FP32_EPS_F 1.1920928955078125e-07f

// ---------------- workspace layout (bytes) — total 4,369,664 (proven-safe size)
#define OFF_PARTIAL 0u            // float4 [4224] = 67584
#define OFF_FLB     67584u        // double [64]
#define OFF_FLL     68096u        // double [64]
#define OFF_FPN     68608u        // int    [64] (+pad to 68864)
#define OFF_CENEG   68864u        // float  [NB*NN] = 4300800 -> end 4369664

// ===================== K1: per-anchor =====================
__global__ __launch_bounds__(256) void k_perdata(
    const float* __restrict__ p_bboxs, const float* __restrict__ g_bboxs,
    const float* __restrict__ p_labels, const int* __restrict__ g_labels,
    const float* __restrict__ ancs,
    float* __restrict__ ce_neg, float4* __restrict__ partial)
{
    __shared__ float lab[256 * NC];            // 21504 B
    __shared__ float st[4];                    // pos, sl1, ce

    const int tid = threadIdx.x;
    const int b = blockIdx.x / BPB;
    const int j = blockIdx.x - b * BPB;
    const int nbase = j * 256;
    const int nrem = NN - nbase;
    const int nact = nrem < 256 ? nrem : 256;  // 256, or 160 for j==65
    const bool valid = tid < nact;

    if (tid < 4) st[tid] = 0.f;

    // hoist per-thread global loads ABOVE the staging barrier so their HBM
    // latency overlaps the p_labels staging + __syncthreads wait
    float4 p = make_float4(0.f, 0.f, 0.f, 0.f);
    float4 g = make_float4(0.f, 0.f, 1.f, 1.f);
    float4 a = make_float4(0.f, 0.f, 1.f, 1.f);
    int gl = 0;
    const int idx = b * NN + nbase + tid;
    if (valid) {
        p = ((const float4*)p_bboxs)[idx];
        g = ((const float4*)g_bboxs)[idx];
        a = ((const float4*)ancs)[nbase + tid];
        gl = g_labels[idx];
    }

    // stage p_labels tile, coalesced float4 (nact*21 divisible by 4)
    {
        const float4* src = (const float4*)(p_labels + ((size_t)b * NN + nbase) * NC);
        float4* dst = (float4*)lab;
        const int nv = nact * NC / 4;          // 1344 or 840
        for (int t = tid; t < nv; t += 256) dst[t] = src[t];
    }
    __syncthreads();

    if (valid) {
        // regression targets + SmoothL1 (beta=1), summed over 4 coords
        const float tx = 10.0f * (g.x - a.x) / a.z;
        const float ty = 10.0f * (g.y - a.y) / a.w;
        const float tw = 5.0f * __logf(g.z / a.z);
        const float th = 5.0f * __logf(g.w / a.w);
        float sl1 = 0.f, d, ad;
        d = p.x - tx; ad = fabsf(d); sl1 += (ad < 1.f) ? 0.5f * d * d : ad - 0.5f;
        d = p.y - ty; ad = fabsf(d); sl1 += (ad < 1.f) ? 0.5f * d * d : ad - 0.5f;
        d = p.z - tw; ad = fabsf(d); sl1 += (ad < 1.f) ? 0.5f * d * d : ad - 0.5f;
        d = p.w - th; ad = fabsf(d); sl1 += (ad < 1.f) ? 0.5f * d * d : ad - 0.5f;

        // cross entropy: lse - x[gl]
        const float* row = lab + tid * NC;     // stride 21 (odd): 2-way alias, free
        float m = row[0];
        #pragma unroll
        for (int c = 1; c < NC; ++c) m = fmaxf(m, row[c]);
        float s = 0.f;
        #pragma unroll
        for (int c = 0; c < NC; ++c) s += __expf(row[c] - m);
        const float lse = m + __logf(s);
        const float ce = fmaxf(lse - row[gl], 0.f);  // >=0 -> bits order-monotonic

        const bool pos = gl > 0;
        ce_neg[idx] = pos ? 0.f : ce;          // coalesced

        // per-block positive stats (~5 pos threads): LDS atomics only
        if (pos) {
            atomicAdd(&st[0], 1.f);
            atomicAdd(&st[1], sl1);
            atomicAdd(&st[2], ce);
        }
    }
    __syncthreads();
    if (tid == 0) partial[blockIdx.x] = make_float4(st[0], st[1], st[2], 0.f);
}

// ===================== K2: per-batch exact top-k sum =====================
__global__ __launch_bounds__(1024) void k_select(
    const float* __restrict__ ce_neg, const float4* __restrict__ partial,
    double* __restrict__ flb, double* __restrict__ fll, int* __restrict__ fpn)
{
    __shared__ uint4   vals4[NN / 4];          // 67200 B (16B aligned)
    __shared__ uint32_t hist[256];
    __shared__ uint32_t h2[256];
    __shared__ float s_stats[4];
    __shared__ uint32_t s_cur;
    __shared__ int s_need;
    __shared__ double dpart[16];

    uint32_t* vals = (uint32_t*)vals4;
    const int tid = threadIdx.x, lane = tid & 63, wid = tid >> 6;
    const int b = blockIdx.x;

    if (tid < 4) s_stats[tid] = 0.f;
    if (tid < 256) hist[tid] = 0u;
    __syncthreads();

    // ---- load batch values (float4), store LDS (b128), fused ballot-histogram ----
    // bin = bits>>23 (sign always 0). One LDS atomic per DISTINCT bin per wave
    // per component (~7 distinct exponent bins in practice).
    {
        const float4* src = (const float4*)(ce_neg + (size_t)b * NN);
        for (int i = tid; i < NN / 4; i += 1024) {
            const float4 v = src[i];
            const uint4 u = make_uint4(__float_as_uint(v.x), __float_as_uint(v.y),
                                       __float_as_uint(v.z), __float_as_uint(v.w));
            vals4[i] = u;
            uint32_t comp[4] = {u.x, u.y, u.z, u.w};
            #pragma unroll
            for (int c = 0; c < 4; ++c) {
                const uint32_t dg = comp[c] >> 23;
                unsigned long long act = __ballot(true);   // active lanes
                while (act) {
                    const int leader = __ffsll((long long)act) - 1;
                    const uint32_t dl = __shfl(dg, leader);
                    const unsigned long long same = __ballot(dg == dl) & act;
                    if (lane == leader) atomicAdd(&hist[dl], (uint32_t)__popcll(same));
                    act &= ~same;
                }
            }
        }
    }

    // ---- reduce per-block stats (66 entries) ----
    if (tid < BPB) {
        const float4 p0 = partial[b * BPB + tid];
        if (p0.x != 0.f) {
            atomicAdd(&s_stats[0], p0.x);
            atomicAdd(&s_stats[1], p0.y);
            atomicAdd(&s_stats[2], p0.z);
        }
    }
    __syncthreads();

    const int pos = (int)(s_stats[0] + 0.5f);
    int k = 3 * pos;                           // NEG_RATIO
    if (k > NN) k = NN;
    if (k < 1) k = 1;                          // pos==0 masked in k_final

    // ---- coarse pick: wave-parallel suffix scan over 256 bins (descending) ----
    if (wid == 0) {
        uint32_t c4[4]; uint32_t cnt = 0;
        #pragma unroll
        for (int t = 0; t < 4; ++t) { c4[t] = hist[255 - (4 * lane + t)]; cnt += c4[t]; }
        uint32_t ic = cnt;
        #pragma unroll
        for (int off = 1; off < 64; off <<= 1) {
            const uint32_t tc = __shfl_up(ic, off);
            if (lane >= off) ic += tc;
        }
        const int exC = (int)(ic - cnt);
        if (exC < k && k <= (int)ic) {         // exactly one lane
            int need = k - exC;
            #pragma unroll
            for (int t = 0; t < 4; ++t) {
                const int c = (int)c4[t];
                if (need <= c) {
                    s_cur = (uint32_t)(255 - (4 * lane + t)) << 23;
                    s_need = need;
                    break;
                }
                need -= c;
            }
        }
    }
    __syncthreads();

    // ---- exact refine of 23 mantissa bits: (sh,nbins)=(15,256),(7,256),(0,128)
    //      bin-walks are wave-parallel (r6 lesson: tid==0 walk = 3x ~14us serial)
    #pragma unroll
    for (int p = 0; p < 3; ++p) {
        const int sh = (p == 0) ? 15 : (p == 1) ? 7 : 0;
        const uint32_t msk = (p == 0) ? 0xFF800000u : (p == 1) ? 0xFFFF8000u : 0xFFFFFF80u;
        const int per = (p == 2) ? 2 : 4;                  // bins per lane
        const uint32_t nbm1 = (p == 2) ? 127u : 255u;
        const uint32_t bm = nbm1;                          // nb-1

        if (tid < 256) h2[tid] = 0u;
        __syncthreads();
        const uint32_t cur = s_cur;
        for (int i = tid; i < NN; i += 1024) {
            const uint32_t v = vals[i];
            if ((v & msk) == cur) atomicAdd(&h2[(v >> sh) & bm], 1u);  // mantissa ~uniform
        }
        __syncthreads();
        if (wid == 0) {
            uint32_t c4[4]; uint32_t cnt = 0;
            #pragma unroll
            for (int t = 0; t < 4; ++t) {
                if (t < per) { c4[t] = h2[nbm1 - (per * lane + t)]; cnt += c4[t]; }
            }
            uint32_t ic = cnt;
            #pragma unroll
            for (int off = 1; off < 64; off <<= 1) {
                const uint32_t tc = __shfl_up(ic, off);
                if (lane >= off) ic += tc;
            }
            const int exC = (int)(ic - cnt);
            const int need_in = s_need;                    // read before any write (lockstep)
            if (exC < need_in && need_in <= (int)ic) {     // exactly one lane
                int need = need_in - exC;
                #pragma unroll
                for (int t = 0; t < 4; ++t) {
                    if (t < per) {
                        const int c = (int)c4[t];
                        if (need <= c) {
                            s_cur = cur | ((nbm1 - (uint32_t)(per * lane + t)) << sh);
                            s_need = need;
                            break;
                        }
                        need -= c;
                    }
                }
            }
        }
        __syncthreads();                                   // protect next clear / final read
    }

    // ---- tie-exact top-k sum: sum(v > T) + r*T ----
    const uint32_t T = s_cur;
    const int rf = s_need;
    double loc = 0.0;
    for (int i = tid; i < NN; i += 1024) {
        const uint32_t v = vals[i];
        if (v > T) loc += (double)__uint_as_float(v);
    }
    #pragma unroll
    for (int off = 32; off > 0; off >>= 1) loc += __shfl_down(loc, off);
    if (lane == 0) dpart[wid] = loc;
    __syncthreads();
    if (tid == 0) {
        double tot = 0.0;
        for (int w = 0; w < 16; ++w) tot += dpart[w];
        tot += (double)rf * (double)__uint_as_float(T);
        flb[b] = (double)s_stats[1];
        fll[b] = (double)s_stats[2] + tot;
        fpn[b] = pos;
    }
}

// ===================== K3: final reduction over B =====================
__global__ __launch_bounds__(64) void k_final(
    const double* __restrict__ flb, const double* __restrict__ fll,
    const int* __restrict__ fpn, float* __restrict__ out)
{
    const int t = threadIdx.x;                 // 64 == NB
    const double lb = flb[t];
    const double ll = fll[t];
    const int pn = fpn[t];
    const double nm = (pn > 0) ? 1.0 : 0.0;
    const float pf = fmaxf((float)pn, FP32_EPS_F);
    const double inv = nm / (double)pf;
    double tb = lb * inv;
    double tl = ll * inv;
    double tt = tb + tl;                       // COEFF = (1,1)
    #pragma unroll
    for (int off = 32; off > 0; off >>= 1) {
        tt += __shfl_down(tt, off);
        tb += __shfl_down(tb, off);
        tl += __shfl_down(tl, off);
    }
    if (t == 0) {
        out[0] = (float)(tt / (double)NB);
        out[1] = (float)(tb / (double)NB);
        out[2] = (float)(tl / (double)NB);
    }
}

// ===================== launcher =====================
extern "C" void kernel_launch(void* const* d_in, const int* in_sizes, int n_in,
                              void* d_out, int out_size, void* d_ws, size_t ws_size,
                              hipStream_t stream)
{
    const float* p_bboxs  = (const float*)d_in[0];
    const float* g_bboxs  = (const float*)d_in[1];
    const float* p_labels = (const float*)d_in[2];
    const int*   g_labels = (const int*)d_in[3];
    const float* ancs     = (const float*)d_in[4];
    float* out = (float*)d_out;

    char* ws = (char*)d_ws;
    float4* partial = (float4*)(ws + OFF_PARTIAL);
    double* flb     = (double*)(ws + OFF_FLB);
    double* fll     = (double*)(ws + OFF_FLL);
    int*    fpn     = (int*)   (ws + OFF_FPN);
    float*  ce_neg  = (float*) (ws + OFF_CENEG);

    // no memset: every workspace byte read is written first (no global atomics)

    k_perdata<<<NBLK1, 256, 0, stream>>>(
        p_bboxs, g_bboxs, p_labels, g_labels, ancs, ce_neg, partial);

    k_select<<<NB, 1024, 0, stream>>>(ce_neg, partial, flb, fll, fpn);

    k_final<<<1, 64, 0, stream>>>(flb, fll, fpn, out);
}

// Round 9
// 185.593 us; speedup vs baseline: 1.2218x; 1.0549x over previous
//
#include <hip/hip_runtime.h>
#include <hip/hip_bf16.h>
#include <stdint.h>

// ObjectDetectionLoss (SSD MultiBox) — MI355X / gfx950
// B=64, N=16800, C=21. Output: 3 fp32 scalars.
//
// Round-9 = round-8 resubmit (r8 died to GPUAcquisitionTimeout before the
// kernel ever ran; experiment still pending). Lessons: r2 = no hot global
// atomics; r3 = no clustered LDS-atomic hist; r6 = no tid==0 serial bin-walks;
// r7 = k_perdata is latency-bound (52us vs 21us HBM floor): 21.5KB LDS tile
// caps 7 blocks/CU and the load->stage->barrier->compute chain convoys waves
// behind HBM latency.
// => K1 drops LDS staging entirely: per-thread scalar reads of the 21 logits
// (lane-stride-84B rows; c=0 pulls the wave's whole 5.4KB span into L1, rest
// are L1 hits), no hot-path barriers, 8 waves/SIMD via low VGPR.
//
//   K1 k_perdata (64x66 blocks, batch-aligned): sl1/ce per anchor -> ce_neg;
//      per-block pos stats (LDS, ~5 threads) -> plain float4 stores.
//   K2 k_select (64x1024): load batch values once (float4 -> LDS b128) with
//      fused 256-bin ballot-histogram; wave-parallel suffix-scan pick at every
//      level (coarse 256 + refine 256/256/128) -> exact k-th value T;
//      sum(v>T)+r*T (tie-exact fp64).   [unchanged from r7]
//   K3 k_final (1x64): reduce over batches.   [unchanged]

#define NB 64
#define NN 16800
#define NC 21
#define BPB 66                    // blocks per batch (66*256 = 16896 >= 16800)
#define NBLK1 (NB * BPB)          // 4224
#define FP32_EPS_F 1.1920928955078125e-07f

// ---------------- workspace layout (bytes) — total 4,369,664 (proven-safe size)
#define OFF_PARTIAL 0u            // float4 [4224] = 67584
#define OFF_FLB     67584u        // double [64]
#define OFF_FLL     68096u        // double [64]
#define OFF_FPN     68608u        // int    [64] (+pad to 68864)
#define OFF_CENEG   68864u        // float  [NB*NN] = 4300800 -> end 4369664

// ===================== K1: per-anchor (LDS-free hot path) =====================
__global__ __launch_bounds__(256) void k_perdata(
    const float* __restrict__ p_bboxs, const float* __restrict__ g_bboxs,
    const float* __restrict__ p_labels, const int* __restrict__ g_labels,
    const float* __restrict__ ancs,
    float* __restrict__ ce_neg, float4* __restrict__ partial)
{
    __shared__ float st[4];                    // pos, sl1, ce

    const int tid = threadIdx.x;
    const int b = blockIdx.x / BPB;
    const int j = blockIdx.x - b * BPB;
    const int nbase = j * 256;
    const int nrem = NN - nbase;
    const int nact = nrem < 256 ? nrem : 256;  // 256, or 160 for j==65
    const bool valid = tid < nact;

    if (tid < 4) st[tid] = 0.f;
    __syncthreads();                           // init before any pos-thread atomic

    if (valid) {
        const int idx = b * NN + nbase + tid;
        const float4 p = ((const float4*)p_bboxs)[idx];
        const float4 g = ((const float4*)g_bboxs)[idx];
        const float4 a = ((const float4*)ancs)[nbase + tid];
        const int gl = g_labels[idx];

        // per-thread row of 21 logits -> registers. Lane stride is 84B, so the
        // wave's first scalar load touches every 128B line of its 5.4KB span;
        // the remaining 20 loads are L1 hits. No LDS, no staging barrier.
        const float* row = p_labels + (size_t)idx * NC;
        float x[NC];
        #pragma unroll
        for (int c = 0; c < NC; ++c) x[c] = row[c];

        // regression targets + SmoothL1 (beta=1), summed over 4 coords
        const float tx = 10.0f * (g.x - a.x) / a.z;
        const float ty = 10.0f * (g.y - a.y) / a.w;
        const float tw = 5.0f * __logf(g.z / a.z);
        const float th = 5.0f * __logf(g.w / a.w);
        float sl1 = 0.f, d, ad;
        d = p.x - tx; ad = fabsf(d); sl1 += (ad < 1.f) ? 0.5f * d * d : ad - 0.5f;
        d = p.y - ty; ad = fabsf(d); sl1 += (ad < 1.f) ? 0.5f * d * d : ad - 0.5f;
        d = p.z - tw; ad = fabsf(d); sl1 += (ad < 1.f) ? 0.5f * d * d : ad - 0.5f;
        d = p.w - th; ad = fabsf(d); sl1 += (ad < 1.f) ? 0.5f * d * d : ad - 0.5f;

        // cross entropy: lse - x[gl]
        float m = x[0];
        #pragma unroll
        for (int c = 1; c < NC; ++c) m = fmaxf(m, x[c]);
        float s = 0.f;
        #pragma unroll
        for (int c = 0; c < NC; ++c) s += __expf(x[c] - m);
        const float lse = m + __logf(s);
        const float ce = fmaxf(lse - x[gl], 0.f);  // >=0 -> bits order-monotonic

        const bool pos = gl > 0;
        ce_neg[idx] = pos ? 0.f : ce;          // coalesced

        // per-block positive stats (~5 pos threads): LDS atomics only
        if (pos) {
            atomicAdd(&st[0], 1.f);
            atomicAdd(&st[1], sl1);
            atomicAdd(&st[2], ce);
        }
    }
    __syncthreads();
    if (tid == 0) partial[blockIdx.x] = make_float4(st[0], st[1], st[2], 0.f);
}

// ===================== K2: per-batch exact top-k sum (unchanged, r7-proven) =====================
__global__ __launch_bounds__(1024) void k_select(
    const float* __restrict__ ce_neg, const float4* __restrict__ partial,
    double* __restrict__ flb, double* __restrict__ fll, int* __restrict__ fpn)
{
    __shared__ uint4   vals4[NN / 4];          // 67200 B (16B aligned)
    __shared__ uint32_t hist[256];
    __shared__ uint32_t h2[256];
    __shared__ float s_stats[4];
    __shared__ uint32_t s_cur;
    __shared__ int s_need;
    __shared__ double dpart[16];

    uint32_t* vals = (uint32_t*)vals4;
    const int tid = threadIdx.x, lane = tid & 63, wid = tid >> 6;
    const int b = blockIdx.x;

    if (tid < 4) s_stats[tid] = 0.f;
    if (tid < 256) hist[tid] = 0u;
    __syncthreads();

    // ---- load batch values (float4), store LDS (b128), fused ballot-histogram ----
    {
        const float4* src = (const float4*)(ce_neg + (size_t)b * NN);
        for (int i = tid; i < NN / 4; i += 1024) {
            const float4 v = src[i];
            const uint4 u = make_uint4(__float_as_uint(v.x), __float_as_uint(v.y),
                                       __float_as_uint(v.z), __float_as_uint(v.w));
            vals4[i] = u;
            uint32_t comp[4] = {u.x, u.y, u.z, u.w};
            #pragma unroll
            for (int c = 0; c < 4; ++c) {
                const uint32_t dg = comp[c] >> 23;
                unsigned long long act = __ballot(true);   // active lanes
                while (act) {
                    const int leader = __ffsll((long long)act) - 1;
                    const uint32_t dl = __shfl(dg, leader);
                    const unsigned long long same = __ballot(dg == dl) & act;
                    if (lane == leader) atomicAdd(&hist[dl], (uint32_t)__popcll(same));
                    act &= ~same;
                }
            }
        }
    }

    // ---- reduce per-block stats (66 entries) ----
    if (tid < BPB) {
        const float4 p0 = partial[b * BPB + tid];
        if (p0.x != 0.f) {
            atomicAdd(&s_stats[0], p0.x);
            atomicAdd(&s_stats[1], p0.y);
            atomicAdd(&s_stats[2], p0.z);
        }
    }
    __syncthreads();

    const int pos = (int)(s_stats[0] + 0.5f);
    int k = 3 * pos;                           // NEG_RATIO
    if (k > NN) k = NN;
    if (k < 1) k = 1;                          // pos==0 masked in k_final

    // ---- coarse pick: wave-parallel suffix scan over 256 bins (descending) ----
    if (wid == 0) {
        uint32_t c4[4]; uint32_t cnt = 0;
        #pragma unroll
        for (int t = 0; t < 4; ++t) { c4[t] = hist[255 - (4 * lane + t)]; cnt += c4[t]; }
        uint32_t ic = cnt;
        #pragma unroll
        for (int off = 1; off < 64; off <<= 1) {
            const uint32_t tc = __shfl_up(ic, off);
            if (lane >= off) ic += tc;
        }
        const int exC = (int)(ic - cnt);
        if (exC < k && k <= (int)ic) {         // exactly one lane
            int need = k - exC;
            #pragma unroll
            for (int t = 0; t < 4; ++t) {
                const int c = (int)c4[t];
                if (need <= c) {
                    s_cur = (uint32_t)(255 - (4 * lane + t)) << 23;
                    s_need = need;
                    break;
                }
                need -= c;
            }
        }
    }
    __syncthreads();

    // ---- exact refine of 23 mantissa bits: (sh,nbins)=(15,256),(7,256),(0,128)
    //      bin-walks wave-parallel (r6 lesson)
    #pragma unroll
    for (int p = 0; p < 3; ++p) {
        const int sh = (p == 0) ? 15 : (p == 1) ? 7 : 0;
        const uint32_t msk = (p == 0) ? 0xFF800000u : (p == 1) ? 0xFFFF8000u : 0xFFFFFF80u;
        const int per = (p == 2) ? 2 : 4;                  // bins per lane
        const uint32_t nbm1 = (p == 2) ? 127u : 255u;
        const uint32_t bm = nbm1;                          // nb-1

        if (tid < 256) h2[tid] = 0u;
        __syncthreads();
        const uint32_t cur = s_cur;
        for (int i = tid; i < NN; i += 1024) {
            const uint32_t v = vals[i];
            if ((v & msk) == cur) atomicAdd(&h2[(v >> sh) & bm], 1u);  // mantissa ~uniform
        }
        __syncthreads();
        if (wid == 0) {
            uint32_t c4[4]; uint32_t cnt = 0;
            #pragma unroll
            for (int t = 0; t < 4; ++t) {
                if (t < per) { c4[t] = h2[nbm1 - (per * lane + t)]; cnt += c4[t]; }
            }
            uint32_t ic = cnt;
            #pragma unroll
            for (int off = 1; off < 64; off <<= 1) {
                const uint32_t tc = __shfl_up(ic, off);
                if (lane >= off) ic += tc;
            }
            const int exC = (int)(ic - cnt);
            const int need_in = s_need;                    // read before write (lockstep)
            if (exC < need_in && need_in <= (int)ic) {     // exactly one lane
                int need = need_in - exC;
                #pragma unroll
                for (int t = 0; t < 4; ++t) {
                    if (t < per) {
                        const int c = (int)c4[t];
                        if (need <= c) {
                            s_cur = cur | ((nbm1 - (uint32_t)(per * lane + t)) << sh);
                            s_need = need;
                            break;
                        }
                        need -= c;
                    }
                }
            }
        }
        __syncthreads();                                   // protect next clear / final read
    }

    // ---- tie-exact top-k sum: sum(v > T) + r*T ----
    const uint32_t T = s_cur;
    const int rf = s_need;
    double loc = 0.0;
    for (int i = tid; i < NN; i += 1024) {
        const uint32_t v = vals[i];
        if (v > T) loc += (double)__uint_as_float(v);
    }
    #pragma unroll
    for (int off = 32; off > 0; off >>= 1) loc += __shfl_down(loc, off);
    if (lane == 0) dpart[wid] = loc;
    __syncthreads();
    if (tid == 0) {
        double tot = 0.0;
        for (int w = 0; w < 16; ++w) tot += dpart[w];
        tot += (double)rf * (double)__uint_as_float(T);
        flb[b] = (double)s_stats[1];
        fll[b] = (double)s_stats[2] + tot;
        fpn[b] = pos;
    }
}

// ===================== K3: final reduction over B (unchanged) =====================
__global__ __launch_bounds__(64) void k_final(
    const double* __restrict__ flb, const double* __restrict__ fll,
    const int* __restrict__ fpn, float* __restrict__ out)
{
    const int t = threadIdx.x;                 // 64 == NB
    const double lb = flb[t];
    const double ll = fll[t];
    const int pn = fpn[t];
    const double nm = (pn > 0) ? 1.0 : 0.0;
    const float pf = fmaxf((float)pn, FP32_EPS_F);
    const double inv = nm / (double)pf;
    double tb = lb * inv;
    double tl = ll * inv;
    double tt = tb + tl;                       // COEFF = (1,1)
    #pragma unroll
    for (int off = 32; off > 0; off >>= 1) {
        tt += __shfl_down(tt, off);
        tb += __shfl_down(tb, off);
        tl += __shfl_down(tl, off);
    }
    if (t == 0) {
        out[0] = (float)(tt / (double)NB);
        out[1] = (float)(tb / (double)NB);
        out[2] = (float)(tl / (double)NB);
    }
}

// ===================== launcher =====================
extern "C" void kernel_launch(void* const* d_in, const int* in_sizes, int n_in,
                              void* d_out, int out_size, void* d_ws, size_t ws_size,
                              hipStream_t stream)
{
    const float* p_bboxs  = (const float*)d_in[0];
    const float* g_bboxs  = (const float*)d_in[1];
    const float* p_labels = (const float*)d_in[2];
    const int*   g_labels = (const int*)d_in[3];
    const float* ancs     = (const float*)d_in[4];
    float* out = (float*)d_out;

    char* ws = (char*)d_ws;
    float4* partial = (float4*)(ws + OFF_PARTIAL);
    double* flb     = (double*)(ws + OFF_FLB);
    double* fll     = (double*)(ws + OFF_FLL);
    int*    fpn     = (int*)   (ws + OFF_FPN);
    float*  ce_neg  = (float*) (ws + OFF_CENEG);

    // no memset: every workspace byte read is written first (no global atomics)

    k_perdata<<<NBLK1, 256, 0, stream>>>(
        p_bboxs, g_bboxs, p_labels, g_labels, ancs, ce_neg, partial);

    k_select<<<NB, 1024, 0, stream>>>(ce_neg, partial, flb, fll, fpn);

    k_final<<<1, 64, 0, stream>>>(flb, fll, fpn, out);
}